// Round 3
// baseline (235.354 us; speedup 1.0000x reference)
//
#include <hip/hip_runtime.h>

// z = x @ W.T - b (65536x512 @ (256x512)^T) -> row-wise projection onto
// {y: |1^T y|<=S, ||y||^2<=R2}. Projection is affine per row (y = a*z + b0),
// fused into the GEMM epilogue via per-row (t, zz) reductions.
//
// R5 restructure vs R3 (R3's counted-vmcnt pipeline was a perfect null vs R2
// -> time is pipeline-structure-invariant; attack the staging path instead):
//  - B (bf16 W, 256 KB) is L2-resident: load fragments DIRECT from global to
//    registers at consume time. No B LDS, no global_load_lds, no manual vmcnt.
//  - A double-buffered in LDS (2 x 16 KB, XOR-swizzled), ONE __syncthreads()
//    per K-tile (was 2 barriers + glds queue coupling).
//  - A global loads issued a full tile ahead (compiler-managed waits).
// Numerics bit-identical to R2/R3: same bf16 values, same MFMA order, same
// epilogue.

typedef __bf16 bf16x8 __attribute__((ext_vector_type(8)));
typedef float f32x4 __attribute__((ext_vector_type(4)));

#define BM 128
#define BN 256
#define BK 64
#define THREADS 512

__device__ __forceinline__ unsigned short f2bf(float f) {
    unsigned u = __builtin_bit_cast(unsigned, f);
    u += 0x7fffu + ((u >> 16) & 1u);     // RNE
    return (unsigned short)(u >> 16);
}

// one-time: W fp32 [256][512] -> bf16 row-major in workspace
__global__ void wconv_kernel(const float* __restrict__ W,
                             unsigned short* __restrict__ Wb) {
    int i = (blockIdx.x * 256 + threadIdx.x) * 4;
    float4 v = *(const float4*)(W + i);
    ushort4 h;
    h.x = f2bf(v.x); h.y = f2bf(v.y); h.z = f2bf(v.z); h.w = f2bf(v.w);
    *(ushort4*)(Wb + i) = h;
}

__global__ __launch_bounds__(THREADS, 4)
void proj_gemm_kernel(const float* __restrict__ x,
                      const unsigned short* __restrict__ Wb,
                      const float* __restrict__ b,
                      float* __restrict__ out) {
    __shared__ alignas(16) unsigned short Abuf[2][BM * BK];   // 2 x 16384 B

    const int tid  = threadIdx.x;
    const int lane = tid & 63;
    const int wv   = tid >> 6;        // 0..7
    const int wm   = wv >> 2;         // m-half (0..1)
    const int wn   = wv & 3;          // n-quarter (0..3)
    const int ln   = lane & 15;
    const int quad = lane >> 4;
    const int m0   = blockIdx.x * BM;

    // A staging coords: 128 rows x 16 float4-chunks, 512 threads -> 4 rows each
    const int arow = tid >> 4;        // 0..31
    const int kq   = tid & 15;
    const float* xbase = x + (long)(m0 + arow) * 512 + kq * 4;

    // A LDS write byte offsets (fixed per thread): row*128 + kq*8, XOR-swizzled
    unsigned awb[4];
    #pragma unroll
    for (int p = 0; p < 4; ++p) {
        const int row = arow + p * 32;
        awb[p] = (unsigned)((row * 128 + kq * 8) ^ ((row & 7) << 4));
    }

    f32x4 acc[4][4];
    #pragma unroll
    for (int mi = 0; mi < 4; ++mi)
        #pragma unroll
        for (int ni = 0; ni < 4; ++ni)
            acc[mi][ni] = (f32x4){0.f, 0.f, 0.f, 0.f};

    float4 areg[4];

    auto load_A = [&](int kt) {
        const int k0 = kt * BK;
        #pragma unroll
        for (int p = 0; p < 4; ++p)
            areg[p] = *(const float4*)(xbase + (long)p * 32 * 512 + k0);
    };
    auto write_A = [&](int buf) {
        #pragma unroll
        for (int p = 0; p < 4; ++p) {
            ushort4 h;
            h.x = f2bf(areg[p].x); h.y = f2bf(areg[p].y);
            h.z = f2bf(areg[p].z); h.w = f2bf(areg[p].w);
            *(ushort4*)((char*)Abuf[buf] + awb[p]) = h;
        }
    };

    // ---- prologue: tile 0 into buf 0 --------------------------------------
    load_A(0);
    write_A(0);
    __syncthreads();

    // ---- main K-loop: 8 tiles, A double-buffered, 1 barrier/tile -----------
    for (int kt = 0; kt < 8; ++kt) {
        const int cur = kt & 1;
        if (kt < 7) load_A(kt + 1);          // issue next A loads early

        const int k0 = kt * BK;
        #pragma unroll
        for (int ks = 0; ks < 2; ++ks) {
            // B fragments direct from global (L2-resident 256 KB W)
            bf16x8 bf[4];
            #pragma unroll
            for (int ni = 0; ni < 4; ++ni) {
                const int r = wn * 64 + ni * 16 + ln;
                bf[ni] = *(const bf16x8*)(Wb + (long)r * 512 + k0 + ks * 32 + quad * 8);
            }
            #pragma unroll
            for (int mi = 0; mi < 4; ++mi) {
                const int row = wm * 64 + mi * 16 + ln;
                const unsigned arb =
                    (unsigned)(row * 128 + ((((ks << 2) | quad) ^ (ln & 7)) << 4));
                bf16x8 af = *(const bf16x8*)((const char*)Abuf[cur] + arb);
                #pragma unroll
                for (int ni = 0; ni < 4; ++ni)
                    acc[mi][ni] = __builtin_amdgcn_mfma_f32_16x16x32_bf16(
                        af, bf[ni], acc[mi][ni], 0, 0, 0);
            }
        }

        if (kt < 7) write_A(cur ^ 1);        // stage A(t+1) into other buffer
        __syncthreads();
    }

    // bias before row reductions
    float bb[4];
    #pragma unroll
    for (int ni = 0; ni < 4; ++ni) bb[ni] = b[wn * 64 + ni * 16 + ln];
    #pragma unroll
    for (int mi = 0; mi < 4; ++mi)
        #pragma unroll
        for (int ni = 0; ni < 4; ++ni)
            #pragma unroll
            for (int r = 0; r < 4; ++r)
                acc[mi][ni][r] -= bb[ni];

    float* P  = (float*)&Abuf[0][0];  // 128 rows x {4 waves x (t,zz)} = 4 KB
    float* AB = P + 128 * 8;          // 128 x (alpha,beta)

    // per-row partials over this wave's 64 cols (cols indexed by ni,ln)
    #pragma unroll
    for (int mi = 0; mi < 4; ++mi) {
        #pragma unroll
        for (int r = 0; r < 4; ++r) {
            float s1 = 0.f, s2 = 0.f;
            #pragma unroll
            for (int ni = 0; ni < 4; ++ni) {
                float v = acc[mi][ni][r];
                s1 += v; s2 += v * v;
            }
            #pragma unroll
            for (int off = 1; off < 16; off <<= 1) {
                s1 += __shfl_xor(s1, off, 64);
                s2 += __shfl_xor(s2, off, 64);
            }
            if (ln == 0) {
                int row = wm * 64 + mi * 16 + quad * 4 + r;
                P[row * 8 + wn * 2 + 0] = s1;
                P[row * 8 + wn * 2 + 1] = s2;
            }
        }
    }
    __syncthreads();

    // one thread per row: KKT case analysis -> (alpha, beta)
    if (tid < 128) {
        int row = tid;
        float t  = P[row*8+0] + P[row*8+2] + P[row*8+4] + P[row*8+6];
        float zz = P[row*8+1] + P[row*8+3] + P[row*8+5] + P[row*8+7];
        const float S = 0.1f, R2 = 0.02f, nf = 256.f, inv_n = 1.f / 256.f;
        float tc    = fminf(fmaxf(t, -S), S);
        float beta1 = (tc - t) * inv_n;
        float ny1   = zz + 2.f * beta1 * t + nf * beta1 * beta1;
        float alpha, beta;
        if (ny1 <= R2) {
            alpha = 1.f; beta = beta1;
        } else {
            float znorm = sqrtf(fmaxf(zz, 1e-12f));
            float scale = fminf(1.f, 0.14142135623730951f / znorm);
            if (fabsf(t) * scale <= S) {
                alpha = scale; beta = 0.f;
            } else {
                float denom = fmaxf(nf * zz - t * t, 1e-12f);
                float c  = sqrtf(5.11f / denom);             // n*R2 - S^2
                float sp = (t > 0.f) ? S : ((t < 0.f) ? -S : 0.f);
                alpha = c; beta = (sp - c * t) * inv_n;
            }
        }
        AB[row*2+0] = alpha;
        AB[row*2+1] = beta;
    }
    __syncthreads();

    // apply y = alpha*z + beta, store
    #pragma unroll
    for (int mi = 0; mi < 4; ++mi) {
        #pragma unroll
        for (int r = 0; r < 4; ++r) {
            int row = wm * 64 + mi * 16 + quad * 4 + r;
            float alpha = AB[row*2+0];
            float beta  = AB[row*2+1];
            float* orow = out + (long)(m0 + row) * 256 + wn * 64 + ln;
            #pragma unroll
            for (int ni = 0; ni < 4; ++ni)
                orow[ni*16] = alpha * acc[mi][ni][r] + beta;
        }
    }
}

extern "C" void kernel_launch(void* const* d_in, const int* in_sizes, int n_in,
                              void* d_out, int out_size, void* d_ws, size_t ws_size,
                              hipStream_t stream) {
    const float* x = (const float*)d_in[0];   // [65536, 512]
    const float* W = (const float*)d_in[1];   // [256, 512]
    const float* b = (const float*)d_in[2];   // [256]
    float* out = (float*)d_out;               // [65536, 256]
    unsigned short* Wb = (unsigned short*)d_ws; // 256KB bf16 W

    const int Dout = in_sizes[2];             // 256
    const int Din  = in_sizes[1] / Dout;      // 512
    const int Btot = in_sizes[0] / Din;       // 65536

    wconv_kernel<<<(Dout * Din) / (256 * 4), 256, 0, stream>>>(W, Wb);
    proj_gemm_kernel<<<Btot / BM, THREADS, 0, stream>>>(x, Wb, b, out);
}

// Round 4
// 228.650 us; speedup vs baseline: 1.0293x; 1.0293x over previous
//
#include <hip/hip_runtime.h>

// z = x @ W.T - b (65536x512 @ (256x512)^T) -> row-wise projection onto
// {y: |1^T y|<=S, ||y||^2<=R2}. Projection is affine per row (y = a*z + b0),
// fused into the GEMM epilogue via per-row (t, zz) reductions.
//
// R6 vs R2/R3/R5 evidence:
//  - R3 (counted-vmcnt pipeline) was an exact null -> intra-block scheduling
//    doesn't matter. R5 (B direct from L2 at consume time) regressed 72->86us
//    -> latency exposure matters; keep B staged via global_load_lds.
//  - R5 counters: all pipes <10%, hbm 20% -> latency/serialization-bound with
//    2 big 8-wave barrier domains per CU.
//  - R6: BM=32, 256-thread blocks (4 waves), LDS ~37KB -> 4 independent
//    barrier domains per CU (grid 2048, 8 queued/CU). acc halves to 32 VGPR.
//    Same glds chunk-swizzled B path, same staged-A convert, same epilogue.

typedef __bf16 bf16x8 __attribute__((ext_vector_type(8)));
typedef float f32x4 __attribute__((ext_vector_type(4)));

#define BM 32
#define BN 256
#define BK 64
#define THREADS 256
#define APITCH 144   // A-tile row pitch in BYTES (128B data + 16B pad, 16B-aligned)

__device__ __forceinline__ unsigned short f2bf(float f) {
    unsigned u = __builtin_bit_cast(unsigned, f);
    u += 0x7fffu + ((u >> 16) & 1u);     // RNE
    return (unsigned short)(u >> 16);
}

// one-time: W fp32 [256][512] -> bf16 row-major in workspace
__global__ void wconv_kernel(const float* __restrict__ W,
                             unsigned short* __restrict__ Wb) {
    int i = (blockIdx.x * 256 + threadIdx.x) * 4;
    float4 v = *(const float4*)(W + i);
    ushort4 h;
    h.x = f2bf(v.x); h.y = f2bf(v.y); h.z = f2bf(v.z); h.w = f2bf(v.w);
    *(ushort4*)(Wb + i) = h;
}

__global__ __launch_bounds__(THREADS, 4)
void proj_gemm_kernel(const float* __restrict__ x,
                      const unsigned short* __restrict__ Wb,
                      const float* __restrict__ b,
                      float* __restrict__ out) {
    __shared__ alignas(16) unsigned short Bbuf[BN * BK];        // 32768 B, chunk-swizzled
    __shared__ alignas(16) unsigned char  Abuf[BM * APITCH];    // 4608 B, padded pitch

    const int tid  = threadIdx.x;
    const int lane = tid & 63;
    const int wn   = tid >> 6;        // 0..3 : n-quarter (cols wn*64..+63)
    const int ln   = lane & 15;
    const int quad = lane >> 4;
    const int m0   = blockIdx.x * BM;

    // A staging: 32 rows x 16 float4-chunks; 8 threads/row, 2 chunks each
    const int arow = tid >> 3;        // 0..31
    const int kq   = tid & 7;         // chunks kq and kq+8
    const float* xbase = x + (long)(m0 + arow) * 512 + kq * 4;

    // B staging via global_load_lds: 8 issues/wave, 16B/lane.
    // flat chunk f = (wn*8+j)*64 + lane; row = f>>3; LDS pos holds global
    // chunk (pos ^ (row&7)) -> pre-swizzle source chunk cg.
    const int b_r0 = wn * 64 + (lane >> 3);          // +8 per issue j
    const int b_cg = (lane & 7) ^ (lane >> 3);       // 16B chunk within row

    f32x4 acc[2][4];
    #pragma unroll
    for (int mi = 0; mi < 2; ++mi)
        #pragma unroll
        for (int ni = 0; ni < 4; ++ni)
            acc[mi][ni] = (f32x4){0.f, 0.f, 0.f, 0.f};

    for (int kt = 0; kt < 8; ++kt) {
        const int k0 = kt * BK;
        __syncthreads();
        // stage B tile (256 rows x 64 k): 4 waves x 8 issues x 1KB
        #pragma unroll
        for (int j = 0; j < 8; ++j) {
            const unsigned short* src =
                Wb + (long)(b_r0 + j * 8) * 512 + k0 + b_cg * 8;
            __builtin_amdgcn_global_load_lds(
                (const __attribute__((address_space(1))) void*)src,
                (__attribute__((address_space(3))) void*)(unsigned long)(unsigned int)
                    (unsigned long)(uintptr_t)&Bbuf[(wn * 8 + j) * 512],
                16, 0, 0);
        }
        // stage A tile (32 rows x 64 k): fp32 -> bf16 -> padded LDS
        {
            float4 v0 = *(const float4*)(xbase + k0);
            float4 v1 = *(const float4*)(xbase + k0 + 32);
            ushort4 h0, h1;
            h0.x = f2bf(v0.x); h0.y = f2bf(v0.y); h0.z = f2bf(v0.z); h0.w = f2bf(v0.w);
            h1.x = f2bf(v1.x); h1.y = f2bf(v1.y); h1.z = f2bf(v1.z); h1.w = f2bf(v1.w);
            *(ushort4*)(Abuf + arow * APITCH + kq * 8)      = h0;
            *(ushort4*)(Abuf + arow * APITCH + kq * 8 + 64) = h1;
        }
        __syncthreads();   // drains vmcnt(0)+lgkmcnt(0): glds + ds_writes visible

        #pragma unroll
        for (int ks = 0; ks < 2; ++ks) {
            bf16x8 bf[4];
            #pragma unroll
            for (int ni = 0; ni < 4; ++ni) {
                const int r  = wn * 64 + ni * 16 + ln;
                const int cc = (ks * 4 + quad) ^ (ln & 7);   // un-swizzle
                bf[ni] = *(const bf16x8*)&Bbuf[r * 64 + cc * 8];
            }
            #pragma unroll
            for (int mi = 0; mi < 2; ++mi) {
                const int row = mi * 16 + ln;
                bf16x8 af = *(const bf16x8*)
                    (Abuf + row * APITCH + ks * 64 + quad * 16);
                #pragma unroll
                for (int ni = 0; ni < 4; ++ni)
                    acc[mi][ni] = __builtin_amdgcn_mfma_f32_16x16x32_bf16(
                        af, bf[ni], acc[mi][ni], 0, 0, 0);
            }
        }
    }

    // bias before row reductions
    float bb[4];
    #pragma unroll
    for (int ni = 0; ni < 4; ++ni) bb[ni] = b[wn * 64 + ni * 16 + ln];
    #pragma unroll
    for (int mi = 0; mi < 2; ++mi)
        #pragma unroll
        for (int ni = 0; ni < 4; ++ni)
            #pragma unroll
            for (int r = 0; r < 4; ++r)
                acc[mi][ni][r] -= bb[ni];

    __syncthreads();                  // all A/B LDS reads done before reuse
    float* P  = (float*)Abuf;         // 32 rows x {4 waves x (t,zz)} = 1 KB
    float* AB = P + 32 * 8;           // 32 x (alpha,beta) = 256 B

    // per-row partials over this wave's 64 cols (cols indexed by ni,ln)
    #pragma unroll
    for (int mi = 0; mi < 2; ++mi) {
        #pragma unroll
        for (int r = 0; r < 4; ++r) {
            float s1 = 0.f, s2 = 0.f;
            #pragma unroll
            for (int ni = 0; ni < 4; ++ni) {
                float v = acc[mi][ni][r];
                s1 += v; s2 += v * v;
            }
            #pragma unroll
            for (int off = 1; off < 16; off <<= 1) {
                s1 += __shfl_xor(s1, off, 64);
                s2 += __shfl_xor(s2, off, 64);
            }
            if (ln == 0) {
                int row = mi * 16 + quad * 4 + r;
                P[row * 8 + wn * 2 + 0] = s1;
                P[row * 8 + wn * 2 + 1] = s2;
            }
        }
    }
    __syncthreads();

    // one thread per row: KKT case analysis -> (alpha, beta)
    if (tid < 32) {
        int row = tid;
        float t  = P[row*8+0] + P[row*8+2] + P[row*8+4] + P[row*8+6];
        float zz = P[row*8+1] + P[row*8+3] + P[row*8+5] + P[row*8+7];
        const float S = 0.1f, R2 = 0.02f, nf = 256.f, inv_n = 1.f / 256.f;
        float tc    = fminf(fmaxf(t, -S), S);
        float beta1 = (tc - t) * inv_n;
        float ny1   = zz + 2.f * beta1 * t + nf * beta1 * beta1;
        float alpha, beta;
        if (ny1 <= R2) {
            alpha = 1.f; beta = beta1;
        } else {
            float znorm = sqrtf(fmaxf(zz, 1e-12f));
            float scale = fminf(1.f, 0.14142135623730951f / znorm);
            if (fabsf(t) * scale <= S) {
                alpha = scale; beta = 0.f;
            } else {
                float denom = fmaxf(nf * zz - t * t, 1e-12f);
                float c  = sqrtf(5.11f / denom);             // n*R2 - S^2
                float sp = (t > 0.f) ? S : ((t < 0.f) ? -S : 0.f);
                alpha = c; beta = (sp - c * t) * inv_n;
            }
        }
        AB[row*2+0] = alpha;
        AB[row*2+1] = beta;
    }
    __syncthreads();

    // apply y = alpha*z + beta, store
    #pragma unroll
    for (int mi = 0; mi < 2; ++mi) {
        #pragma unroll
        for (int r = 0; r < 4; ++r) {
            int row = mi * 16 + quad * 4 + r;
            float alpha = AB[row*2+0];
            float beta  = AB[row*2+1];
            float* orow = out + (long)(m0 + row) * 256 + wn * 64 + ln;
            #pragma unroll
            for (int ni = 0; ni < 4; ++ni)
                orow[ni*16] = alpha * acc[mi][ni][r] + beta;
        }
    }
}

extern "C" void kernel_launch(void* const* d_in, const int* in_sizes, int n_in,
                              void* d_out, int out_size, void* d_ws, size_t ws_size,
                              hipStream_t stream) {
    const float* x = (const float*)d_in[0];   // [65536, 512]
    const float* W = (const float*)d_in[1];   // [256, 512]
    const float* b = (const float*)d_in[2];   // [256]
    float* out = (float*)d_out;               // [65536, 256]
    unsigned short* Wb = (unsigned short*)d_ws; // 256KB bf16 W

    const int Dout = in_sizes[2];             // 256
    const int Din  = in_sizes[1] / Dout;      // 512
    const int Btot = in_sizes[0] / Din;       // 65536

    wconv_kernel<<<(Dout * Din) / (256 * 4), 256, 0, stream>>>(W, Wb);
    proj_gemm_kernel<<<Btot / BM, THREADS, 0, stream>>>(x, Wb, b, out);
}